// Round 9
// baseline (123.929 us; speedup 1.0000x reference)
//
#include <hip/hip_runtime.h>
#include <math.h>

#define NLM   1024      // landmarks per batch
#define NB    2         // batches
#define OPS   40        // coarse grid size per axis
#define DIM   128       // output volume size per axis
#define OPS3  (OPS*OPS*OPS)
#define DIM3  (DIM*DIM*DIM)

// coarse tile: 4(p) x 4(q) x 8(r) cells = 128 cells, 1 cell/thread
#define P_T 4
#define Q_T 4
#define R_T 8
#define NP  (OPS/P_T)    // 10
#define NQ  (OPS/Q_T)    // 10
#define NR  (OPS/R_T)    // 5
#define MARGIN 0.30f     // exp2(-288.5*0.09) ~ 2e-8 -> negligible truncation

// exp(-d2/ALPHA) = exp2(K2*d2), K2 = -1/(ALPHA*ln2); M2 = -2*K2
#define K2f  (-288.5390081777927f)
#define M2f  ( 577.0780163555854f)

// warp kernel staging tile (per wave): ROWS_MAX (z,y)-rows x NX_MAX floats
#define ROWS_MAX 20
#define NX_MAX   96

// ws layout: coarse : float4[NB*OPS3] @ 0   (2,048,000 bytes)

__device__ __forceinline__ float fexp2(float x) {
#if __has_builtin(__builtin_amdgcn_exp2f)
    return __builtin_amdgcn_exp2f(x);
#else
    return exp2f(x);
#endif
}

// One block per 4x4x8 coarse tile (500 tiles x 2 batches), 128 threads.
__global__ __launch_bounds__(128)
void coarse_kernel(const float* __restrict__ coords, const float* __restrict__ offs,
                   float4* __restrict__ C) {
    __shared__ float4 sA[NLM];
    __shared__ float4 sV[NLM];
    __shared__ int sCnt;

    const int t = threadIdx.x;       // 0..127
    const int b = blockIdx.y;
    const int tile = blockIdx.x;     // 0..499
    const int tp = tile / (NQ*NR);
    const int tq = (tile / NR) % NQ;
    const int tr = tile % NR;

    const float step = 2.f / (OPS - 1);
    const float bx0 = -1.f + step * (tr*R_T)          - MARGIN;
    const float bx1 = -1.f + step * (tr*R_T + R_T-1)  + MARGIN;
    const float by0 = -1.f + step * (tq*Q_T)          - MARGIN;
    const float by1 = -1.f + step * (tq*Q_T + Q_T-1)  + MARGIN;
    const float bz0 = -1.f + step * (tp*P_T)          - MARGIN;
    const float bz1 = -1.f + step * (tp*P_T + P_T-1)  + MARGIN;

    if (t == 0) sCnt = 0;
    __syncthreads();

    for (int n = t; n < NLM; n += 128) {
        const float* cp = coords + (b*NLM + n)*3;
        const float* op = offs   + (b*NLM + n)*3;
        float ox = op[0], oy = op[1], oz = op[2];
        float cx = cp[0] + ox, cy = cp[1] + oy, cz = cp[2] + oz;
        if (cx >= bx0 && cx <= bx1 && cy >= by0 && cy <= by1 &&
            cz >= bz0 && cz <= bz1) {
            int idx = atomicAdd(&sCnt, 1);
            sA[idx] = make_float4(cx, cy, cz, K2f*(cx*cx + cy*cy + cz*cz));
            sV[idx] = make_float4(-ox, -oy, -oz, 0.f);
        }
    }
    __syncthreads();
    const int cnt = sCnt;

    const int lp = t >> 5;
    const int lq = (t >> 3) & 3;
    const int lr = t & 7;
    const float gx = -1.f + step * (tr*R_T + lr);
    const float gy = -1.f + step * (tq*Q_T + lq);
    const float gz = -1.f + step * (tp*P_T + lp);
    const float h  = K2f * (gx*gx + gy*gy + gz*gz);

    float aS = 0.f, aX = 0.f, aY = 0.f, aZ = 0.f;
    for (int n = 0; n < cnt; ++n) {
        float4 a = sA[n];            // LDS broadcast
        float4 v = sV[n];
        float u   = fmaf(gx, a.x, fmaf(gy, a.y, gz*a.z));
        float arg = fmaf(M2f, u, h + a.w);   // K2*||g-c||^2
        float e   = fexp2(arg);
        aS += e;
        aX = fmaf(e, v.x, aX);
        aY = fmaf(e, v.y, aY);
        aZ = fmaf(e, v.z, aZ);
    }

    const int p = tp*P_T + lp, q = tq*Q_T + lq, r = tr*R_T + lr;
    const float inv = 1.01f / (aS + 0.01f);
    C[b*OPS3 + (p*OPS + q)*OPS + r] = make_float4(aX*inv, aY*inv, aZ*inv, 0.f);
}

__device__ __forceinline__ void axis_interp(int t, int& a0, int& a1, float& w) {
    float c = fmaxf(0.3125f * (float)t - 0.34375f, 0.f);
    float f = floorf(c);
    a0 = (int)f;
    a1 = min(a0 + 1, OPS - 1);
    w = c - f;
}

__device__ __forceinline__ float4 lerp4(float4 a, float4 b, float t) {
    return make_float4(a.x + t*(b.x - a.x),
                       a.y + t*(b.y - a.y),
                       a.z + t*(b.z - a.z),
                       0.f);
}

// 4-byte-aligned float2 load (fallback path only)
typedef float vf2 __attribute__((ext_vector_type(2)));
struct __attribute__((packed, aligned(4))) P2 { vf2 v; };
__device__ __forceinline__ vf2 load2(const float* p) {
    return ((const P2*)p)->v;
}

// Per-voxel gather state. Rows are CLAMPED (not wrapped) — in-bounds; the
// masked weights zero any OOB contribution, so clamped-row values are inert.
struct AW {
    int za, zb, ya, yb, xs;
    float e0, e1, wy0, wy1, wz0, wz1;
};

__device__ __forceinline__ AW make_aw(float px, float py, float pz) {
    AW s;
    float xf = floorf(px), yf = floorf(py), zf = floorf(pz);
    int x0 = (int)xf, y0 = (int)yf, z0 = (int)zf;
    float ax = px - xf, ay = py - yf, az = pz - zf;

    float wx0 = ((unsigned)x0     < 128u) ? (1.f - ax) : 0.f;
    float wx1 = ((unsigned)(x0+1) < 128u) ? ax         : 0.f;
    s.wy0 = ((unsigned)y0     < 128u) ? (1.f - ay) : 0.f;
    s.wy1 = ((unsigned)(y0+1) < 128u) ? ay         : 0.f;
    s.wz0 = ((unsigned)z0     < 128u) ? (1.f - az) : 0.f;
    s.wz1 = ((unsigned)(z0+1) < 128u) ? az         : 0.f;

    s.xs = min(max(x0, 0), 126);           // pair [xs, xs+1] always in-bounds
    int d = x0 - s.xs;
    s.e0 = (d == 0) ? wx0 : ((d == -1) ? wx1 : 0.f);
    s.e1 = (d == 0) ? wx1 : ((d ==  1) ? wx0 : 0.f);

    s.ya = min(max(y0,   0), 127);
    s.yb = min(max(y0+1, 0), 127);
    s.za = min(max(z0,   0), 127);
    s.zb = min(max(z0+1, 0), 127);
    return s;
}

__device__ __forceinline__ int wave_min(int v) {
    #pragma unroll
    for (int m = 32; m; m >>= 1) v = min(v, __shfl_xor(v, m, 64));
    return v;
}
__device__ __forceinline__ int wave_max(int v) {
    #pragma unroll
    for (int m = 32; m; m >>= 1) v = max(v, __shfl_xor(v, m, 64));
    return v;
}

__device__ __forceinline__ float accum8(float a0, float a1, float b0, float b1,
                                        float c0, float c1, float d0, float d1,
                                        const AW& s) {
    float w00 = s.wz0*s.wy0, w01 = s.wz0*s.wy1;
    float w10 = s.wz1*s.wy0, w11 = s.wz1*s.wy1;
    float r = a0 * (w00*s.e0);
    r = fmaf(a1, w00*s.e1, r);
    r = fmaf(b0, w01*s.e0, r);
    r = fmaf(b1, w01*s.e1, r);
    r = fmaf(c0, w10*s.e0, r);
    r = fmaf(c1, w10*s.e1, r);
    r = fmaf(d0, w11*s.e0, r);
    r = fmaf(d1, w11*s.e1, r);
    return r;
}

// 256-thread blocks = 4 waves; wave w handles one (b,i,j) k-line; each lane
// 2 voxels (k=lane, k=lane+64). Per 64-voxel segment: wave-reduce the tap
// bounding box, stage it into a wave-private LDS tile with COALESCED global
// loads (TA cost ~1/7 of a gather), take the 8 taps from LDS. Wave-uniform
// fallback to the round-7 pair-gather if the box exceeds tile capacity.
// XCD slab swizzle: slot g&7 owns a contiguous 32-i slab.
__global__ __launch_bounds__(256)
void warp_kernel(const float* __restrict__ mask, const float4* __restrict__ C,
                 float* __restrict__ out) {
    __shared__ float4 sF[4][OPS];                  // per-wave k-line flow
    __shared__ float sTile[4][ROWS_MAX*NX_MAX];    // per-wave staging tile

    const int g = blockIdx.x;                        // 0..8191
    const int w = threadIdx.x >> 6;                  // wave 0..3
    const int lane = threadIdx.x & 63;
    const int line = ((g & 7) << 12) + ((g >> 3) << 2) + w;  // b*DIM^2+i*DIM+j
    const int j = line & (DIM-1);
    const int i = (line >> 7) & (DIM-1);
    const int b = line >> 14;

    int i0,i1,j0,j1; float ti,tj;
    axis_interp(i, i0, i1, ti);
    axis_interp(j, j0, j1, tj);

    const float4* Cb = C + b*OPS3;
    if (lane < OPS) {
        float4 c00 = Cb[(i0*OPS + j0)*OPS + lane];
        float4 c01 = Cb[(i0*OPS + j1)*OPS + lane];
        float4 c10 = Cb[(i1*OPS + j0)*OPS + lane];
        float4 c11 = Cb[(i1*OPS + j1)*OPS + lane];
        sF[w][lane] = lerp4(lerp4(c00, c01, tj), lerp4(c10, c11, tj), ti);
    }
    // no barrier: sF[w] / sTile[w] are wave-private (lockstep)

    const float* M = mask + b * DIM3;
    const float s127 = 2.f / (DIM - 1);
    const float yb2 = -1.f + s127 * (float)j;
    const float zb2 = -1.f + s127 * (float)i;

    float res[2];
    #pragma unroll
    for (int c = 0; c < 2; ++c) {
        const int k = lane + (c << 6);
        int k0,k1; float tk;
        axis_interp(k, k0, k1, tk);
        float4 fl = lerp4(sF[w][k0], sF[w][k1], tk);
        float x = -1.f + s127 * (float)k + fl.x;
        float y = yb2 + fl.y;
        float z = zb2 + fl.z;
        AW s = make_aw(((x + 1.f) * (float)DIM - 1.f) * 0.5f,
                       ((y + 1.f) * (float)DIM - 1.f) * 0.5f,
                       ((z + 1.f) * (float)DIM - 1.f) * 0.5f);

        // wave-uniform tap bounding box (clamped coords -> always in-bounds)
        const int minZ = wave_min(s.za), maxZ = wave_max(s.zb);
        const int minY = wave_min(s.ya), maxY = wave_max(s.yb);
        const int minX = wave_min(s.xs), maxX = wave_max(s.xs);
        const int nz = maxZ - minZ + 1;
        const int ny = maxY - minY + 1;
        const int nx = maxX - minX + 2;            // covers xs..xs+1

        if (nz*ny <= ROWS_MAX && nx <= NX_MAX) {
            float* T = sTile[w];
            // coalesced staging of the box
            int row = 0;
            for (int zz = minZ; zz <= maxZ; ++zz) {
                for (int yy = minY; yy <= maxY; ++yy, ++row) {
                    const float* src = M + (zz << 14) + (yy << 7) + minX;
                    float* dst = T + row*NX_MAX;
                    for (int xx = lane; xx < nx; xx += 64)
                        dst[xx] = src[xx];
                }
            }
            // taps from LDS (in-wave DS ordering; compiler inserts waits)
            const int xl = s.xs - minX;
            const float* p00 = T + ((s.za - minZ)*ny + (s.ya - minY))*NX_MAX + xl;
            const float* p01 = T + ((s.za - minZ)*ny + (s.yb - minY))*NX_MAX + xl;
            const float* p10 = T + ((s.zb - minZ)*ny + (s.ya - minY))*NX_MAX + xl;
            const float* p11 = T + ((s.zb - minZ)*ny + (s.yb - minY))*NX_MAX + xl;
            res[c] = accum8(p00[0], p00[1], p01[0], p01[1],
                            p10[0], p10[1], p11[0], p11[1], s);
        } else {
            // fallback: round-7 pair-gather (clamped rows, same values)
            const int r0 = (s.za << 14) + (s.ya << 7);
            const int r1 = (s.za << 14) + (s.yb << 7);
            const int r2 = (s.zb << 14) + (s.ya << 7);
            const int r3 = (s.zb << 14) + (s.yb << 7);
            vf2 t0 = load2(M + r0 + s.xs);
            vf2 t1 = load2(M + r1 + s.xs);
            vf2 t2 = load2(M + r2 + s.xs);
            vf2 t3 = load2(M + r3 + s.xs);
            res[c] = accum8(t0.x, t0.y, t1.x, t1.y, t2.x, t2.y, t3.x, t3.y, s);
        }
    }

    out[(line << 7) + lane]      = res[0];
    out[(line << 7) + lane + 64] = res[1];
}

extern "C" void kernel_launch(void* const* d_in, const int* in_sizes, int n_in,
                              void* d_out, int out_size, void* d_ws, size_t ws_size,
                              hipStream_t stream) {
    const float* mask   = (const float*)d_in[0];   // (2,1,128,128,128)
    const float* coords = (const float*)d_in[1];   // (2,1024,3)
    const float* offs   = (const float*)d_in[2];   // (2,1024,3)
    float* out = (float*)d_out;

    float4* coarse = (float4*)d_ws;                // NB*OPS3 float4

    dim3 g1(NP*NQ*NR, NB);                         // 500 x 2 blocks
    coarse_kernel<<<g1, 128, 0, stream>>>(coords, offs, coarse);

    warp_kernel<<<NB*DIM*DIM/4, 256, 0, stream>>>(mask, coarse, out);
}

// Round 10
// 97.929 us; speedup vs baseline: 1.2655x; 1.2655x over previous
//
#include <hip/hip_runtime.h>
#include <math.h>

#define NLM   1024      // landmarks per batch
#define NB    2         // batches
#define OPS   40        // coarse grid size per axis
#define DIM   128       // output volume size per axis
#define OPS3  (OPS*OPS*OPS)
#define DIM3  (DIM*DIM*DIM)

// coarse tile: 4(p) x 4(q) x 8(r) cells = 128 cells, 1 cell/thread
#define P_T 4
#define Q_T 4
#define R_T 8
#define NP  (OPS/P_T)    // 10
#define NQ  (OPS/Q_T)    // 10
#define NR  (OPS/R_T)    // 5
#define MARGIN 0.30f     // exp2(-288.5*0.09) ~ 2e-8 -> negligible truncation

// exp(-d2/ALPHA) = exp2(K2*d2), K2 = -1/(ALPHA*ln2); M2 = -2*K2
#define K2f  (-288.5390081777927f)
#define M2f  ( 577.0780163555854f)

// ws layout: coarse : float4[NB*OPS3] @ 0   (2,048,000 bytes)

__device__ __forceinline__ float fexp2(float x) {
#if __has_builtin(__builtin_amdgcn_exp2f)
    return __builtin_amdgcn_exp2f(x);
#else
    return exp2f(x);
#endif
}

// One block per 4x4x8 coarse tile (500 tiles x 2 batches), 128 threads.
__global__ __launch_bounds__(128)
void coarse_kernel(const float* __restrict__ coords, const float* __restrict__ offs,
                   float4* __restrict__ C) {
    __shared__ float4 sA[NLM];
    __shared__ float4 sV[NLM];
    __shared__ int sCnt;

    const int t = threadIdx.x;       // 0..127
    const int b = blockIdx.y;
    const int tile = blockIdx.x;     // 0..499
    const int tp = tile / (NQ*NR);
    const int tq = (tile / NR) % NQ;
    const int tr = tile % NR;

    const float step = 2.f / (OPS - 1);
    const float bx0 = -1.f + step * (tr*R_T)          - MARGIN;
    const float bx1 = -1.f + step * (tr*R_T + R_T-1)  + MARGIN;
    const float by0 = -1.f + step * (tq*Q_T)          - MARGIN;
    const float by1 = -1.f + step * (tq*Q_T + Q_T-1)  + MARGIN;
    const float bz0 = -1.f + step * (tp*P_T)          - MARGIN;
    const float bz1 = -1.f + step * (tp*P_T + P_T-1)  + MARGIN;

    if (t == 0) sCnt = 0;
    __syncthreads();

    for (int n = t; n < NLM; n += 128) {
        const float* cp = coords + (b*NLM + n)*3;
        const float* op = offs   + (b*NLM + n)*3;
        float ox = op[0], oy = op[1], oz = op[2];
        float cx = cp[0] + ox, cy = cp[1] + oy, cz = cp[2] + oz;
        if (cx >= bx0 && cx <= bx1 && cy >= by0 && cy <= by1 &&
            cz >= bz0 && cz <= bz1) {
            int idx = atomicAdd(&sCnt, 1);
            sA[idx] = make_float4(cx, cy, cz, K2f*(cx*cx + cy*cy + cz*cz));
            sV[idx] = make_float4(-ox, -oy, -oz, 0.f);
        }
    }
    __syncthreads();
    const int cnt = sCnt;

    const int lp = t >> 5;
    const int lq = (t >> 3) & 3;
    const int lr = t & 7;
    const float gx = -1.f + step * (tr*R_T + lr);
    const float gy = -1.f + step * (tq*Q_T + lq);
    const float gz = -1.f + step * (tp*P_T + lp);
    const float h  = K2f * (gx*gx + gy*gy + gz*gz);

    float aS = 0.f, aX = 0.f, aY = 0.f, aZ = 0.f;
    for (int n = 0; n < cnt; ++n) {
        float4 a = sA[n];            // LDS broadcast
        float4 v = sV[n];
        float u   = fmaf(gx, a.x, fmaf(gy, a.y, gz*a.z));
        float arg = fmaf(M2f, u, h + a.w);   // K2*||g-c||^2
        float e   = fexp2(arg);
        aS += e;
        aX = fmaf(e, v.x, aX);
        aY = fmaf(e, v.y, aY);
        aZ = fmaf(e, v.z, aZ);
    }

    const int p = tp*P_T + lp, q = tq*Q_T + lq, r = tr*R_T + lr;
    const float inv = 1.01f / (aS + 0.01f);
    C[b*OPS3 + (p*OPS + q)*OPS + r] = make_float4(aX*inv, aY*inv, aZ*inv, 0.f);
}

__device__ __forceinline__ void axis_interp(int t, int& a0, int& a1, float& w) {
    float c = fmaxf(0.3125f * (float)t - 0.34375f, 0.f);
    float f = floorf(c);
    a0 = (int)f;
    a1 = min(a0 + 1, OPS - 1);
    w = c - f;
}

__device__ __forceinline__ float4 lerp4(float4 a, float4 b, float t) {
    return make_float4(a.x + t*(b.x - a.x),
                       a.y + t*(b.y - a.y),
                       a.z + t*(b.z - a.z),
                       0.f);
}

// 4-byte-aligned float2 load (compiler emits global_load_dwordx2 under HW
// unaligned mode; degrades to 2 dwords otherwise — no worse than scalar).
typedef float vf2 __attribute__((ext_vector_type(2)));
struct __attribute__((packed, aligned(4))) P2 { vf2 v; };
__device__ __forceinline__ vf2 load2(const float* p) {
    return ((const P2*)p)->v;
}

// Per-voxel gather state: 4 wrapped row bases + pair base xs + pair weights.
// Wrapped (&127) indices safe: the masked weight for any OOB tap is 0.
struct AW {
    int r0, r1, r2, r3, xs;
    float e0, e1, wy0, wy1, wz0, wz1;
};

__device__ __forceinline__ AW make_aw(float px, float py, float pz) {
    AW s;
    float xf = floorf(px), yf = floorf(py), zf = floorf(pz);
    int x0 = (int)xf, y0 = (int)yf, z0 = (int)zf;
    float ax = px - xf, ay = py - yf, az = pz - zf;

    float wx0 = ((unsigned)x0     < 128u) ? (1.f - ax) : 0.f;
    float wx1 = ((unsigned)(x0+1) < 128u) ? ax         : 0.f;
    s.wy0 = ((unsigned)y0     < 128u) ? (1.f - ay) : 0.f;
    s.wy1 = ((unsigned)(y0+1) < 128u) ? ay         : 0.f;
    s.wz0 = ((unsigned)z0     < 128u) ? (1.f - az) : 0.f;
    s.wz1 = ((unsigned)(z0+1) < 128u) ? az         : 0.f;

    s.xs = min(max(x0, 0), 126);           // pair [xs, xs+1] always in-bounds
    int d = x0 - s.xs;                     // 0 interior, -1 left edge, >=1 right
    s.e0 = (d == 0) ? wx0 : ((d == -1) ? wx1 : 0.f);
    s.e1 = (d == 0) ? wx1 : ((d ==  1) ? wx0 : 0.f);

    int ya = (y0 & 127) << 7, yb2 = ((y0+1) & 127) << 7;
    int za = (z0 & 127) << 14, zb2 = ((z0+1) & 127) << 14;
    s.r0 = za + ya;  s.r1 = za + yb2;
    s.r2 = zb2 + ya; s.r3 = zb2 + yb2;
    return s;
}

// 512-thread blocks = 8 waves; wave w handles one (b,i,j) k-line; each lane
// 2 voxels (k=lane, k=lane+64). Round-7 pair-gather structure (best known:
// 4 lane-addresses/voxel); 8 waves/block packs 4 blocks/CU = 2048 thr/CU.
// XCD slab swizzle: slot g&7 owns a contiguous 32-i slab.
__global__ __launch_bounds__(512)
void warp_kernel(const float* __restrict__ mask, const float4* __restrict__ C,
                 float* __restrict__ out) {
    __shared__ float4 sF[8][OPS];    // per-wave k-line flow

    const int g = blockIdx.x;                        // 0..4095
    const int w = threadIdx.x >> 6;                  // wave 0..7
    const int lane = threadIdx.x & 63;
    const int line = ((g & 7) << 12) + ((g >> 3) << 3) + w;  // b*DIM^2+i*DIM+j
    const int j = line & (DIM-1);
    const int i = (line >> 7) & (DIM-1);
    const int b = line >> 14;

    int i0,i1,j0,j1; float ti,tj;
    axis_interp(i, i0, i1, ti);
    axis_interp(j, j0, j1, tj);

    const float4* Cb = C + b*OPS3;
    if (lane < OPS) {
        float4 c00 = Cb[(i0*OPS + j0)*OPS + lane];
        float4 c01 = Cb[(i0*OPS + j1)*OPS + lane];
        float4 c10 = Cb[(i1*OPS + j0)*OPS + lane];
        float4 c11 = Cb[(i1*OPS + j1)*OPS + lane];
        sF[w][lane] = lerp4(lerp4(c00, c01, tj), lerp4(c10, c11, tj), ti);
    }
    // no barrier: sF[w] is wave-private (produced & consumed in lockstep)

    const float* M = mask + b * DIM3;
    const float s127 = 2.f / (DIM - 1);
    const float yb = -1.f + s127 * (float)j;
    const float zb = -1.f + s127 * (float)i;

    // phase A: addresses + weights for both voxels
    AW aw[2];
    #pragma unroll
    for (int c = 0; c < 2; ++c) {
        const int k = lane + (c << 6);
        int k0,k1; float tk;
        axis_interp(k, k0, k1, tk);
        float4 fl = lerp4(sF[w][k0], sF[w][k1], tk);
        float x = -1.f + s127 * (float)k + fl.x;
        float y = yb + fl.y;
        float z = zb + fl.z;
        aw[c] = make_aw(((x + 1.f) * (float)DIM - 1.f) * 0.5f,
                        ((y + 1.f) * (float)DIM - 1.f) * 0.5f,
                        ((z + 1.f) * (float)DIM - 1.f) * 0.5f);
    }

    // phase B: all 8 pair-taps in flight before any accumulation
    vf2 t0[4], t1[4];
    {
        const AW& s = aw[0];
        t0[0] = load2(M + s.r0 + s.xs);
        t0[1] = load2(M + s.r1 + s.xs);
        t0[2] = load2(M + s.r2 + s.xs);
        t0[3] = load2(M + s.r3 + s.xs);
    }
    {
        const AW& s = aw[1];
        t1[0] = load2(M + s.r0 + s.xs);
        t1[1] = load2(M + s.r1 + s.xs);
        t1[2] = load2(M + s.r2 + s.xs);
        t1[3] = load2(M + s.r3 + s.xs);
    }

    // phase C: accumulate + store
    float res[2];
    #pragma unroll
    for (int c = 0; c < 2; ++c) {
        const AW& s = aw[c];
        const vf2* tv = c ? t1 : t0;
        float w00 = s.wz0*s.wy0, w01 = s.wz0*s.wy1;
        float w10 = s.wz1*s.wy0, w11 = s.wz1*s.wy1;
        float r;
        r = tv[0].x * (w00*s.e0);
        r = fmaf(tv[0].y, w00*s.e1, r);
        r = fmaf(tv[1].x, w01*s.e0, r);
        r = fmaf(tv[1].y, w01*s.e1, r);
        r = fmaf(tv[2].x, w10*s.e0, r);
        r = fmaf(tv[2].y, w10*s.e1, r);
        r = fmaf(tv[3].x, w11*s.e0, r);
        r = fmaf(tv[3].y, w11*s.e1, r);
        res[c] = r;
    }
    out[(line << 7) + lane]      = res[0];
    out[(line << 7) + lane + 64] = res[1];
}

extern "C" void kernel_launch(void* const* d_in, const int* in_sizes, int n_in,
                              void* d_out, int out_size, void* d_ws, size_t ws_size,
                              hipStream_t stream) {
    const float* mask   = (const float*)d_in[0];   // (2,1,128,128,128)
    const float* coords = (const float*)d_in[1];   // (2,1024,3)
    const float* offs   = (const float*)d_in[2];   // (2,1024,3)
    float* out = (float*)d_out;

    float4* coarse = (float4*)d_ws;                // NB*OPS3 float4

    dim3 g1(NP*NQ*NR, NB);                         // 500 x 2 blocks
    coarse_kernel<<<g1, 128, 0, stream>>>(coords, offs, coarse);

    warp_kernel<<<NB*DIM*DIM/8, 512, 0, stream>>>(mask, coarse, out);
}

// Round 11
// 97.786 us; speedup vs baseline: 1.2674x; 1.0015x over previous
//
#include <hip/hip_runtime.h>
#include <math.h>
#include <string.h>

#define NLM   1024      // landmarks per batch
#define NB    2         // batches
#define OPS   40        // coarse grid size per axis
#define DIM   128       // output volume size per axis
#define OPS3  (OPS*OPS*OPS)
#define DIM3  (DIM*DIM*DIM)

// coarse tile: 4(p) x 4(q) x 8(r) cells = 128 cells, 1 cell/thread
#define P_T 4
#define Q_T 4
#define R_T 8
#define NP  (OPS/P_T)    // 10
#define NQ  (OPS/Q_T)    // 10
#define NR  (OPS/R_T)    // 5
#define MARGIN 0.30f     // exp2(-288.5*0.09) ~ 2e-8 -> negligible truncation

// exp(-d2/ALPHA) = exp2(K2*d2), K2 = -1/(ALPHA*ln2); M2 = -2*K2
#define K2f  (-288.5390081777927f)
#define M2f  ( 577.0780163555854f)

// ws layout: coarse : float4[NB*OPS3] @ 0   (2,048,000 bytes)

__device__ __forceinline__ float fexp2(float x) {
#if __has_builtin(__builtin_amdgcn_exp2f)
    return __builtin_amdgcn_exp2f(x);
#else
    return exp2f(x);
#endif
}

// One block per 4x4x8 coarse tile (500 tiles x 2 batches), 128 threads.
__global__ __launch_bounds__(128)
void coarse_kernel(const float* __restrict__ coords, const float* __restrict__ offs,
                   float4* __restrict__ C) {
    __shared__ float4 sA[NLM];
    __shared__ float4 sV[NLM];
    __shared__ int sCnt;

    const int t = threadIdx.x;       // 0..127
    const int b = blockIdx.y;
    const int tile = blockIdx.x;     // 0..499
    const int tp = tile / (NQ*NR);
    const int tq = (tile / NR) % NQ;
    const int tr = tile % NR;

    const float step = 2.f / (OPS - 1);
    const float bx0 = -1.f + step * (tr*R_T)          - MARGIN;
    const float bx1 = -1.f + step * (tr*R_T + R_T-1)  + MARGIN;
    const float by0 = -1.f + step * (tq*Q_T)          - MARGIN;
    const float by1 = -1.f + step * (tq*Q_T + Q_T-1)  + MARGIN;
    const float bz0 = -1.f + step * (tp*P_T)          - MARGIN;
    const float bz1 = -1.f + step * (tp*P_T + P_T-1)  + MARGIN;

    if (t == 0) sCnt = 0;
    __syncthreads();

    for (int n = t; n < NLM; n += 128) {
        const float* cp = coords + (b*NLM + n)*3;
        const float* op = offs   + (b*NLM + n)*3;
        float ox = op[0], oy = op[1], oz = op[2];
        float cx = cp[0] + ox, cy = cp[1] + oy, cz = cp[2] + oz;
        if (cx >= bx0 && cx <= bx1 && cy >= by0 && cy <= by1 &&
            cz >= bz0 && cz <= bz1) {
            int idx = atomicAdd(&sCnt, 1);
            sA[idx] = make_float4(cx, cy, cz, K2f*(cx*cx + cy*cy + cz*cz));
            sV[idx] = make_float4(-ox, -oy, -oz, 0.f);
        }
    }
    __syncthreads();
    const int cnt = sCnt;

    const int lp = t >> 5;
    const int lq = (t >> 3) & 3;
    const int lr = t & 7;
    const float gx = -1.f + step * (tr*R_T + lr);
    const float gy = -1.f + step * (tq*Q_T + lq);
    const float gz = -1.f + step * (tp*P_T + lp);
    const float h  = K2f * (gx*gx + gy*gy + gz*gz);

    float aS = 0.f, aX = 0.f, aY = 0.f, aZ = 0.f;
    for (int n = 0; n < cnt; ++n) {
        float4 a = sA[n];            // LDS broadcast
        float4 v = sV[n];
        float u   = fmaf(gx, a.x, fmaf(gy, a.y, gz*a.z));
        float arg = fmaf(M2f, u, h + a.w);   // K2*||g-c||^2
        float e   = fexp2(arg);
        aS += e;
        aX = fmaf(e, v.x, aX);
        aY = fmaf(e, v.y, aY);
        aZ = fmaf(e, v.z, aZ);
    }

    const int p = tp*P_T + lp, q = tq*Q_T + lq, r = tr*R_T + lr;
    const float inv = 1.01f / (aS + 0.01f);
    C[b*OPS3 + (p*OPS + q)*OPS + r] = make_float4(aX*inv, aY*inv, aZ*inv, 0.f);
}

__device__ __forceinline__ void axis_interp(int t, int& a0, int& a1, float& w) {
    float c = fmaxf(0.3125f * (float)t - 0.34375f, 0.f);
    float f = floorf(c);
    a0 = (int)f;
    a1 = min(a0 + 1, OPS - 1);
    w = c - f;
}

__device__ __forceinline__ float4 lerp4(float4 a, float4 b, float t) {
    return make_float4(a.x + t*(b.x - a.x),
                       a.y + t*(b.y - a.y),
                       a.z + t*(b.z - a.z),
                       0.f);
}

typedef float vf2 __attribute__((ext_vector_type(2)));

#if __has_builtin(__builtin_amdgcn_make_buffer_rsrc) && \
    __has_builtin(__builtin_amdgcn_raw_ptr_buffer_load_b64)
#define USE_BUF 1
typedef unsigned int v2u __attribute__((ext_vector_type(2)));
__device__ __forceinline__ vf2 bload2(__amdgpu_buffer_rsrc_t R, int voff_bytes) {
    v2u r = __builtin_amdgcn_raw_ptr_buffer_load_b64(R, voff_bytes, 0, 0);
    vf2 f;
    memcpy(&f, &r, 8);
    return f;
}
#else
#define USE_BUF 0
struct __attribute__((packed, aligned(4))) P2 { vf2 v; };
__device__ __forceinline__ vf2 load2(const float* p) {
    return ((const P2*)p)->v;
}
#endif

// Per-voxel gather state with RAW row indices (no wrap/clamp): HW buffer
// bounds-check returns 0 for flat-OOB; any axis-OOB tap has a 0 masked
// weight, so in-flat-bounds garbage rows are inert. x pair base is clamped
// to [0,126] with remapped pair weights (e0,e1), exactly as round 7.
struct AW {
    int r0, r1, r2, r3, xs;   // raw row bases (elements) + clamped pair base
    float e0, e1, wy0, wy1, wz0, wz1;
};

__device__ __forceinline__ AW make_aw(float px, float py, float pz) {
    AW s;
    float xf = floorf(px), yf = floorf(py), zf = floorf(pz);
    int x0 = (int)xf, y0 = (int)yf, z0 = (int)zf;
    float ax = px - xf, ay = py - yf, az = pz - zf;

    float wx0 = ((unsigned)x0     < 128u) ? (1.f - ax) : 0.f;
    float wx1 = ((unsigned)(x0+1) < 128u) ? ax         : 0.f;
    s.wy0 = ((unsigned)y0     < 128u) ? (1.f - ay) : 0.f;
    s.wy1 = ((unsigned)(y0+1) < 128u) ? ay         : 0.f;
    s.wz0 = ((unsigned)z0     < 128u) ? (1.f - az) : 0.f;
    s.wz1 = ((unsigned)(z0+1) < 128u) ? az         : 0.f;

    s.xs = min(max(x0, 0), 126);           // pair [xs, xs+1] in-bounds in x
    int d = x0 - s.xs;                     // 0 interior, -1 left edge, >=1 right
    s.e0 = (d == 0) ? wx0 : ((d == -1) ? wx1 : 0.f);
    s.e1 = (d == 0) ? wx1 : ((d ==  1) ? wx0 : 0.f);

#if USE_BUF
    int ya = y0 << 7, yb2 = (y0+1) << 7;   // RAW (possibly OOB) row bases
    int za = z0 << 14, zb2 = (z0+1) << 14;
#else
    int ya = (y0 & 127) << 7, yb2 = ((y0+1) & 127) << 7;
    int za = (z0 & 127) << 14, zb2 = ((z0+1) & 127) << 14;
#endif
    s.r0 = za + ya;  s.r1 = za + yb2;
    s.r2 = zb2 + ya; s.r3 = zb2 + yb2;
    return s;
}

// 512-thread blocks = 8 waves; wave w handles one (b,i,j) k-line; each lane
// 2 voxels (k=lane, k=lane+64). Round-7 pair-gather structure (4 lane-
// addresses/voxel) with buffer-load OOB handling replacing wrap VALU and
// 32-bit voffsets replacing 64-bit address chains.
// XCD slab swizzle: slot g&7 owns a contiguous 32-i slab.
__global__ __launch_bounds__(512)
void warp_kernel(const float* __restrict__ mask, const float4* __restrict__ C,
                 float* __restrict__ out) {
    __shared__ float4 sF[8][OPS];    // per-wave k-line flow

    const int g = blockIdx.x;                        // 0..4095
    const int w = threadIdx.x >> 6;                  // wave 0..7
    const int lane = threadIdx.x & 63;
    const int line = ((g & 7) << 12) + ((g >> 3) << 3) + w;  // b*DIM^2+i*DIM+j
    const int j = line & (DIM-1);
    const int i = (line >> 7) & (DIM-1);
    const int b = line >> 14;

    int i0,i1,j0,j1; float ti,tj;
    axis_interp(i, i0, i1, ti);
    axis_interp(j, j0, j1, tj);

    const float4* Cb = C + b*OPS3;
    if (lane < OPS) {
        float4 c00 = Cb[(i0*OPS + j0)*OPS + lane];
        float4 c01 = Cb[(i0*OPS + j1)*OPS + lane];
        float4 c10 = Cb[(i1*OPS + j0)*OPS + lane];
        float4 c11 = Cb[(i1*OPS + j1)*OPS + lane];
        sF[w][lane] = lerp4(lerp4(c00, c01, tj), lerp4(c10, c11, tj), ti);
    }
    // no barrier: sF[w] is wave-private (produced & consumed in lockstep)

    const float* M = mask + b * DIM3;
#if USE_BUF
    __amdgpu_buffer_rsrc_t R =
        __builtin_amdgcn_make_buffer_rsrc((void*)M, (short)0,
                                          DIM3 * 4, 0x00020000);
#endif
    const float s127 = 2.f / (DIM - 1);
    const float yb = -1.f + s127 * (float)j;
    const float zb = -1.f + s127 * (float)i;

    // phase A: addresses + weights for both voxels
    AW aw[2];
    #pragma unroll
    for (int c = 0; c < 2; ++c) {
        const int k = lane + (c << 6);
        int k0,k1; float tk;
        axis_interp(k, k0, k1, tk);
        float4 fl = lerp4(sF[w][k0], sF[w][k1], tk);
        float x = -1.f + s127 * (float)k + fl.x;
        float y = yb + fl.y;
        float z = zb + fl.z;
        aw[c] = make_aw(((x + 1.f) * (float)DIM - 1.f) * 0.5f,
                        ((y + 1.f) * (float)DIM - 1.f) * 0.5f,
                        ((z + 1.f) * (float)DIM - 1.f) * 0.5f);
    }

    // phase B: all 8 pair-taps in flight before any accumulation
    vf2 t0[4], t1[4];
#if USE_BUF
    {
        const AW& s = aw[0];
        t0[0] = bload2(R, (s.r0 + s.xs) * 4);
        t0[1] = bload2(R, (s.r1 + s.xs) * 4);
        t0[2] = bload2(R, (s.r2 + s.xs) * 4);
        t0[3] = bload2(R, (s.r3 + s.xs) * 4);
    }
    {
        const AW& s = aw[1];
        t1[0] = bload2(R, (s.r0 + s.xs) * 4);
        t1[1] = bload2(R, (s.r1 + s.xs) * 4);
        t1[2] = bload2(R, (s.r2 + s.xs) * 4);
        t1[3] = bload2(R, (s.r3 + s.xs) * 4);
    }
#else
    {
        const AW& s = aw[0];
        t0[0] = load2(M + s.r0 + s.xs);
        t0[1] = load2(M + s.r1 + s.xs);
        t0[2] = load2(M + s.r2 + s.xs);
        t0[3] = load2(M + s.r3 + s.xs);
    }
    {
        const AW& s = aw[1];
        t1[0] = load2(M + s.r0 + s.xs);
        t1[1] = load2(M + s.r1 + s.xs);
        t1[2] = load2(M + s.r2 + s.xs);
        t1[3] = load2(M + s.r3 + s.xs);
    }
#endif

    // phase C: accumulate (pairwise, packed-FMA friendly) + store
    float res[2];
    #pragma unroll
    for (int c = 0; c < 2; ++c) {
        const AW& s = aw[c];
        const vf2* tv = c ? t1 : t0;
        vf2 e;  e.x = s.e0;  e.y = s.e1;
        vf2 acc;
        acc    = tv[0] * (e * (s.wz0*s.wy0));
        acc   += tv[1] * (e * (s.wz0*s.wy1));
        acc   += tv[2] * (e * (s.wz1*s.wy0));
        acc   += tv[3] * (e * (s.wz1*s.wy1));
        res[c] = acc.x + acc.y;
    }
    out[(line << 7) + lane]      = res[0];
    out[(line << 7) + lane + 64] = res[1];
}

extern "C" void kernel_launch(void* const* d_in, const int* in_sizes, int n_in,
                              void* d_out, int out_size, void* d_ws, size_t ws_size,
                              hipStream_t stream) {
    const float* mask   = (const float*)d_in[0];   // (2,1,128,128,128)
    const float* coords = (const float*)d_in[1];   // (2,1024,3)
    const float* offs   = (const float*)d_in[2];   // (2,1024,3)
    float* out = (float*)d_out;

    float4* coarse = (float4*)d_ws;                // NB*OPS3 float4

    dim3 g1(NP*NQ*NR, NB);                         // 500 x 2 blocks
    coarse_kernel<<<g1, 128, 0, stream>>>(coords, offs, coarse);

    warp_kernel<<<NB*DIM*DIM/8, 512, 0, stream>>>(mask, coarse, out);
}